// Round 1
// baseline (32240.039 us; speedup 1.0000x reference)
//
#include <hip/hip_runtime.h>

// ---------------------------------------------------------------------------
// 2-layer LSTM (B=256,T=512,H=512,DIN=64) + FC, persistent-kernel wavefront.
// Layer pipelining: at wavefront step s, layer0 computes t=s, layer1 t=s-1.
// fp16 MFMA (16x16x32) with fp32 accum; c-state in registers (fp32).
// Grid barrier: two-level device-scope atomic counters in ws.
// ---------------------------------------------------------------------------

typedef _Float16 f16;
typedef _Float16 f16x8 __attribute__((ext_vector_type(8)));
typedef float    f32x4 __attribute__((ext_vector_type(4)));

constexpr int NB   = 256;   // batch
constexpr int NT   = 512;   // time steps
constexpr int NH   = 512;   // hidden
constexpr int NDIN = 64;    // input dim

constexpr int L0_KC = 18;   // K chunks of 32: 64(x) + 512(h0) = 576
constexpr int L1_KC = 32;   // 512(h0) + 512(h1) = 1024
constexpr int L0_IMG_HALVES = 4 * L0_KC * 64 * 8;  // 36864 halves = 73728 B per htile
constexpr int L1_IMG_HALVES = 4 * L1_KC * 64 * 8;  // 65536 halves = 131072 B per htile

// ws layout (bytes), all 256-aligned
constexpr size_t BAR_OFF   = 0;                        // 8 KB barrier counters
constexpr size_t BIAS0_OFF = 8192;                     // 2048 f32
constexpr size_t BIAS1_OFF = 16384;                    // 2048 f32
constexpr size_t H0R_OFF   = 24576;                    // [2][256][512] f16
constexpr size_t H1R_OFF   = H0R_OFF + 524288;         // [2][256][512] f16
constexpr size_t XT_OFF    = H1R_OFF + 524288;         // [512][256][64] f16
constexpr size_t W0I_OFF   = XT_OFF + 16777216;        // 32 htiles * 73728 B
constexpr size_t W1I_OFF   = W0I_OFF + 2359296;        // 32 htiles * 131072 B
constexpr size_t WS_NEED   = W1I_OFF + 4194304;        // ~24.4 MB

// ---------------------------------------------------------------------------
// Prep: swizzle weights (fp32 -> fp16) into MFMA B-fragment order.
// B-frag layout (16x16x32): lane L holds B[k = (L>>4)*8 + j][n = L&15], j=0..7
// Image element order: [htile][nf(=gate)][kc][lane][8 halves]
// ---------------------------------------------------------------------------
__global__ void prep_weights(const float* __restrict__ Wih0, const float* __restrict__ Whh0,
                             const float* __restrict__ Wih1, const float* __restrict__ Whh1,
                             char* __restrict__ ws) {
    int idx = blockIdx.x * 256 + threadIdx.x;
    const int L0_CH = 32 * 4 * L0_KC * 64;   // 147456
    const int L1_CH = 32 * 4 * L1_KC * 64;   // 262144
    if (idx < L0_CH) {
        int lam = idx & 63;
        int kc  = (idx >> 6) % L0_KC;
        int nf  = ((idx >> 6) / L0_KC) & 3;
        int ht  = idx / (64 * L0_KC * 4);
        int g   = nf * NH + ht * 16 + (lam & 15);   // gate row in [0,2048)
        int kb  = kc * 32 + (lam >> 4) * 8;
        f16x8 v;
#pragma unroll
        for (int j = 0; j < 8; ++j) {
            int k = kb + j;
            float val = (k < NDIN) ? Wih0[(size_t)g * NDIN + k]
                                   : Whh0[(size_t)g * NH + (k - NDIN)];
            v[j] = (f16)val;
        }
        f16* dst = (f16*)(ws + W0I_OFF) + (size_t)ht * L0_IMG_HALVES
                 + ((size_t)(nf * L0_KC + kc) * 64 + lam) * 8;
        *(f16x8*)dst = v;
    } else if (idx < L0_CH + L1_CH) {
        int i2  = idx - L0_CH;
        int lam = i2 & 63;
        int kc  = (i2 >> 6) % L1_KC;
        int nf  = ((i2 >> 6) / L1_KC) & 3;
        int ht  = i2 / (64 * L1_KC * 4);
        int g   = nf * NH + ht * 16 + (lam & 15);
        int kb  = kc * 32 + (lam >> 4) * 8;
        f16x8 v;
#pragma unroll
        for (int j = 0; j < 8; ++j) {
            int k = kb + j;
            float val = (k < NH) ? Wih1[(size_t)g * NH + k]
                                 : Whh1[(size_t)g * NH + (k - NH)];
            v[j] = (f16)val;
        }
        f16* dst = (f16*)(ws + W1I_OFF) + (size_t)ht * L1_IMG_HALVES
                 + ((size_t)(nf * L1_KC + kc) * 64 + lam) * 8;
        *(f16x8*)dst = v;
    }
}

// x [B][T][64] fp32 -> xt [T][B][64] fp16 (time-major)
__global__ void prep_x(const float* __restrict__ x, char* __restrict__ ws) {
    int idx = blockIdx.x * 256 + threadIdx.x;          // t*256*8 + b*8 + d8
    if (idx >= NT * NB * 8) return;
    int d8 = idx & 7;
    int b  = (idx >> 3) & 255;
    int t  = idx >> 11;
    const float* src = x + ((size_t)b * NT + t) * NDIN + d8 * 8;
    f16x8 v;
#pragma unroll
    for (int j = 0; j < 8; ++j) v[j] = (f16)src[j];
    f16* dst = (f16*)(ws + XT_OFF) + ((size_t)t * NB + b) * NDIN + d8 * 8;
    *(f16x8*)dst = v;
}

// bias sums + zero barrier area + zero h rings
__global__ void prep_state(const float* __restrict__ bih0, const float* __restrict__ bhh0,
                           const float* __restrict__ bih1, const float* __restrict__ bhh1,
                           char* __restrict__ ws) {
    int idx = blockIdx.x * 256 + threadIdx.x;
    if (idx < 2048) {
        ((float*)(ws + BIAS0_OFF))[idx] = bih0[idx] + bhh0[idx];
    } else if (idx < 4096) {
        int i = idx - 2048;
        ((float*)(ws + BIAS1_OFF))[i] = bih1[i] + bhh1[i];
    } else {
        int c = idx - 4096;
        uint4 z; z.x = z.y = z.z = z.w = 0u;
        if (c < 512) {                       // 8 KB barrier area
            ((uint4*)(ws + BAR_OFF))[c] = z;
        } else if (c < 512 + 65536) {        // both h rings (contiguous 1 MB)
            ((uint4*)(ws + H0R_OFF))[c - 512] = z;
        }
    }
}

// ---------------------------------------------------------------------------
// Persistent kernel
// ---------------------------------------------------------------------------
__device__ __forceinline__ float sigf(float x) { return 1.f / (1.f + __expf(-x)); }
__device__ __forceinline__ float tanhx(float x) { float e = __expf(2.f * x); return 1.f - 2.f / (e + 1.f); }

__global__ __launch_bounds__(256, 1) void lstm_persist(char* __restrict__ ws,
                                                       const float* __restrict__ fcW,
                                                       const float* __restrict__ fcb,
                                                       float* __restrict__ out) {
    extern __shared__ __align__(16) char smem[];
    f16*   sW   = (f16*)smem;                 // W image: up to 128 KB
    float* exch = (float*)(smem + 131072);    // 8 KB g/o exchange

    const int tid  = threadIdx.x;
    const int lam  = tid & 63;
    const int w    = tid >> 6;
    const int mh   = w & 1;          // M half (rows b0+mh*32 .. +31)
    const int nh   = w >> 1;         // N half: 0 -> gates i,f ; 1 -> gates g,o
    const int col  = lam & 15;
    const int quad = lam >> 4;

    const int layer = blockIdx.x >> 7;       // 0..1
    const int bi    = blockIdx.x & 127;
    const int b0    = (bi & 3) * 64;         // 4 B-tiles of 64
    const int ht    = bi >> 2;               // 32 H-tiles of 16
    const int h0c   = ht * 16;
    const int KC    = layer ? L1_KC : L0_KC;

    f16* h0ring = (f16*)(ws + H0R_OFF);
    f16* h1ring = (f16*)(ws + H1R_OFF);
    const f16*   xt   = (const f16*)(ws + XT_OFF);
    const float* bias = (const float*)(ws + (layer ? BIAS1_OFF : BIAS0_OFF));
    const f16*   wimg = (const f16*)(ws + (layer ? W1I_OFF : W0I_OFF))
                      + (size_t)ht * (layer ? L1_IMG_HALVES : L0_IMG_HALVES);

    // Stage this block's W slice into LDS once (lives for all 512 steps).
    {
        const int n16 = KC * 4 * 64;         // uint4 chunks
        const uint4* src = (const uint4*)wimg;
        uint4* dst = (uint4*)sW;
        for (int i = tid; i < n16; i += 256) dst[i] = src[i];
    }
    __syncthreads();

    const float bi_i = bias[0 * NH + h0c + col];
    const float bi_f = bias[1 * NH + h0c + col];
    const float bi_g = bias[2 * NH + h0c + col];
    const float bi_o = bias[3 * NH + h0c + col];

    float cst[2][4];                          // c state (only meaningful in nh==0 waves)
#pragma unroll
    for (int a = 0; a < 2; ++a)
#pragma unroll
        for (int r = 0; r < 4; ++r) cst[a][r] = 0.f;

    unsigned* rootc = (unsigned*)(ws + BAR_OFF);
    unsigned* grpc  = (unsigned*)(ws + BAR_OFF + 256 + (size_t)(blockIdx.x >> 4) * 256);

    const f16x8* sBf = (const f16x8*)sW;
    const int nf0 = nh * 2, nf1 = nh * 2 + 1;
    const int rA0 = b0 + mh * 32 + col;       // A-row (m = lane&15) for m-frag 0; +16 for frag 1

    for (int s = 0; s <= NT; ++s) {
        const bool active = layer ? (s >= 1) : (s < NT);
        if (active) {
            f32x4 acc00 = {0.f,0.f,0.f,0.f}, acc01 = {0.f,0.f,0.f,0.f};
            f32x4 acc10 = {0.f,0.f,0.f,0.f}, acc11 = {0.f,0.f,0.f,0.f};

            if (layer == 0) {
                const f16* xa = xt + (size_t)s * NB * NDIN;
                const f16* hp = h0ring + (size_t)((s + 1) & 1) * (NB * NH);
#pragma unroll
                for (int kc = 0; kc < 2; ++kc) {          // x part (K 0..63)
                    int ko = kc * 32 + quad * 8;
                    f16x8 a0 = *(const f16x8*)(xa + (size_t)rA0 * NDIN + ko);
                    f16x8 a1 = *(const f16x8*)(xa + (size_t)(rA0 + 16) * NDIN + ko);
                    f16x8 w0 = sBf[(nf0 * L0_KC + kc) * 64 + lam];
                    f16x8 w1 = sBf[(nf1 * L0_KC + kc) * 64 + lam];
                    acc00 = __builtin_amdgcn_mfma_f32_16x16x32_f16(a0, w0, acc00, 0, 0, 0);
                    acc01 = __builtin_amdgcn_mfma_f32_16x16x32_f16(a0, w1, acc01, 0, 0, 0);
                    acc10 = __builtin_amdgcn_mfma_f32_16x16x32_f16(a1, w0, acc10, 0, 0, 0);
                    acc11 = __builtin_amdgcn_mfma_f32_16x16x32_f16(a1, w1, acc11, 0, 0, 0);
                }
#pragma unroll
                for (int kc = 2; kc < L0_KC; ++kc) {      // h0_{t-1} part
                    int ko = (kc - 2) * 32 + quad * 8;
                    f16x8 a0 = *(const f16x8*)(hp + (size_t)rA0 * NH + ko);
                    f16x8 a1 = *(const f16x8*)(hp + (size_t)(rA0 + 16) * NH + ko);
                    f16x8 w0 = sBf[(nf0 * L0_KC + kc) * 64 + lam];
                    f16x8 w1 = sBf[(nf1 * L0_KC + kc) * 64 + lam];
                    acc00 = __builtin_amdgcn_mfma_f32_16x16x32_f16(a0, w0, acc00, 0, 0, 0);
                    acc01 = __builtin_amdgcn_mfma_f32_16x16x32_f16(a0, w1, acc01, 0, 0, 0);
                    acc10 = __builtin_amdgcn_mfma_f32_16x16x32_f16(a1, w0, acc10, 0, 0, 0);
                    acc11 = __builtin_amdgcn_mfma_f32_16x16x32_f16(a1, w1, acc11, 0, 0, 0);
                }
            } else {
                const f16* hp0 = h0ring + (size_t)((s - 1) & 1) * (NB * NH);  // h0[t]
                const f16* hp1 = h1ring + (size_t)(s & 1) * (NB * NH);        // h1[t-1]
#pragma unroll
                for (int kc = 0; kc < 16; ++kc) {
                    int ko = kc * 32 + quad * 8;
                    f16x8 a0 = *(const f16x8*)(hp0 + (size_t)rA0 * NH + ko);
                    f16x8 a1 = *(const f16x8*)(hp0 + (size_t)(rA0 + 16) * NH + ko);
                    f16x8 w0 = sBf[(nf0 * L1_KC + kc) * 64 + lam];
                    f16x8 w1 = sBf[(nf1 * L1_KC + kc) * 64 + lam];
                    acc00 = __builtin_amdgcn_mfma_f32_16x16x32_f16(a0, w0, acc00, 0, 0, 0);
                    acc01 = __builtin_amdgcn_mfma_f32_16x16x32_f16(a0, w1, acc01, 0, 0, 0);
                    acc10 = __builtin_amdgcn_mfma_f32_16x16x32_f16(a1, w0, acc10, 0, 0, 0);
                    acc11 = __builtin_amdgcn_mfma_f32_16x16x32_f16(a1, w1, acc11, 0, 0, 0);
                }
#pragma unroll
                for (int kc = 16; kc < 32; ++kc) {
                    int ko = (kc - 16) * 32 + quad * 8;
                    f16x8 a0 = *(const f16x8*)(hp1 + (size_t)rA0 * NH + ko);
                    f16x8 a1 = *(const f16x8*)(hp1 + (size_t)(rA0 + 16) * NH + ko);
                    f16x8 w0 = sBf[(nf0 * L1_KC + kc) * 64 + lam];
                    f16x8 w1 = sBf[(nf1 * L1_KC + kc) * 64 + lam];
                    acc00 = __builtin_amdgcn_mfma_f32_16x16x32_f16(a0, w0, acc00, 0, 0, 0);
                    acc01 = __builtin_amdgcn_mfma_f32_16x16x32_f16(a0, w1, acc01, 0, 0, 0);
                    acc10 = __builtin_amdgcn_mfma_f32_16x16x32_f16(a1, w0, acc10, 0, 0, 0);
                    acc11 = __builtin_amdgcn_mfma_f32_16x16x32_f16(a1, w1, acc11, 0, 0, 0);
                }
            }

            // g/o waves hand their accs to i/f waves; cell update is register-local there.
            if (nh == 1) {
                f32x4* e4 = (f32x4*)exch;
                e4[((mh * 2 + 0) * 2 + 0) * 64 + lam] = acc00;   // mf0, gate g
                e4[((mh * 2 + 0) * 2 + 1) * 64 + lam] = acc01;   // mf0, gate o
                e4[((mh * 2 + 1) * 2 + 0) * 64 + lam] = acc10;   // mf1, gate g
                e4[((mh * 2 + 1) * 2 + 1) * 64 + lam] = acc11;   // mf1, gate o
            }
            __syncthreads();
            if (nh == 0) {
                const f32x4* e4 = (const f32x4*)exch;
                f32x4 gg0 = e4[((mh * 2 + 0) * 2 + 0) * 64 + lam];
                f32x4 oo0 = e4[((mh * 2 + 0) * 2 + 1) * 64 + lam];
                f32x4 gg1 = e4[((mh * 2 + 1) * 2 + 0) * 64 + lam];
                f32x4 oo1 = e4[((mh * 2 + 1) * 2 + 1) * 64 + lam];
                f16* hw = layer ? (h1ring + (size_t)((s - 1) & 1) * (NB * NH))
                                : (h0ring + (size_t)(s & 1) * (NB * NH));
#pragma unroll
                for (int mf = 0; mf < 2; ++mf) {
                    f32x4 ai = mf ? acc10 : acc00;
                    f32x4 af = mf ? acc11 : acc01;
                    f32x4 ag = mf ? gg1 : gg0;
                    f32x4 ao = mf ? oo1 : oo0;
#pragma unroll
                    for (int r = 0; r < 4; ++r) {
                        float iv = ai[r] + bi_i;
                        float fv = af[r] + bi_f;
                        float gv = ag[r] + bi_g;
                        float ov = ao[r] + bi_o;
                        float cc = sigf(fv) * cst[mf][r] + sigf(iv) * tanhx(gv);
                        cst[mf][r] = cc;
                        float hh = sigf(ov) * tanhx(cc);
                        // C/D layout: row = quad*4 + r, col = lane&15
                        hw[(size_t)(b0 + mh * 32 + mf * 16 + quad * 4 + r) * NH + h0c + col] = (f16)hh;
                    }
                }
            }
        }

        // ---- grid barrier (two-level, device scope) ----
        __threadfence();
        __syncthreads();
        if (tid == 0) {
            unsigned prev = __hip_atomic_fetch_add(grpc, 1u, __ATOMIC_ACQ_REL, __HIP_MEMORY_SCOPE_AGENT);
            if ((prev & 15u) == 15u)
                __hip_atomic_fetch_add(rootc, 1u, __ATOMIC_ACQ_REL, __HIP_MEMORY_SCOPE_AGENT);
            const unsigned tgt = (unsigned)(s + 1) * 16u;
            while (__hip_atomic_load(rootc, __ATOMIC_ACQUIRE, __HIP_MEMORY_SCOPE_AGENT) < tgt)
                __builtin_amdgcn_s_sleep(2);
        }
        __syncthreads();
        __threadfence();
    }

    // Final FC: out[b] = fc_b + sum_j fc_W[j] * h2[T-1][b][j]; h1 ring slot (T-1)&1 = 1
    if (blockIdx.x == 0) {
        const f16* hrow = h1ring + (size_t)1 * (NB * NH) + (size_t)tid * NH;
        float acc = fcb[0];
#pragma unroll 4
        for (int j = 0; j < NH; ++j) acc += fcW[j] * (float)hrow[j];
        out[tid] = acc;
    }
}

// ---------------------------------------------------------------------------
extern "C" void kernel_launch(void* const* d_in, const int* in_sizes, int n_in,
                              void* d_out, int out_size, void* d_ws, size_t ws_size,
                              hipStream_t stream) {
    const float* x    = (const float*)d_in[0];
    const float* Wih0 = (const float*)d_in[1];
    const float* Whh0 = (const float*)d_in[2];
    const float* bih0 = (const float*)d_in[3];
    const float* bhh0 = (const float*)d_in[4];
    const float* Wih1 = (const float*)d_in[5];
    const float* Whh1 = (const float*)d_in[6];
    const float* bih1 = (const float*)d_in[7];
    const float* bhh1 = (const float*)d_in[8];
    const float* fcW  = (const float*)d_in[9];
    const float* fcb  = (const float*)d_in[10];
    char*  ws  = (char*)d_ws;
    float* out = (float*)d_out;

    if (ws_size < WS_NEED) {  // deterministic failure instead of corruption
        hipMemsetAsync(d_out, 0, (size_t)out_size * sizeof(float), stream);
        return;
    }

    hipFuncSetAttribute(reinterpret_cast<const void*>(lstm_persist),
                        hipFuncAttributeMaxDynamicSharedMemorySize, 139264);

    prep_weights<<<1600, 256, 0, stream>>>(Wih0, Whh0, Wih1, Whh1, ws);
    prep_x<<<4096, 256, 0, stream>>>(x, ws);
    prep_state<<<274, 256, 0, stream>>>(bih0, bhh0, bih1, bhh1, ws);
    // 256 blocks, 139264 B dynamic LDS -> exactly 1 block/CU on 256 CUs (co-resident)
    lstm_persist<<<256, 256, 139264, stream>>>(ws, fcW, fcb, out);
}

// Round 2
// 8945.934 us; speedup vs baseline: 3.6039x; 3.6039x over previous
//
#include <hip/hip_runtime.h>

// ---------------------------------------------------------------------------
// 2-layer LSTM (B=256,T=512,H=512,DIN=64) + FC, persistent-kernel wavefront.
// Layer pipelining: at wavefront step s, layer0 computes t=s, layer1 t=s-1.
// fp16 MFMA (16x16x32) with fp32 accum; c-state in registers (fp32).
// R2: coherence redesign — h stores are relaxed agent-scope (sc1 write-through
// to LLC), barrier is 1 release-add + relaxed spin + 1 acquire-load PER BLOCK
// (was: per-thread __threadfence -> 131k L2 wb/inv per step, 63 us/step).
// ---------------------------------------------------------------------------

typedef _Float16 f16;
typedef _Float16 f16x8 __attribute__((ext_vector_type(8)));
typedef float    f32x4 __attribute__((ext_vector_type(4)));

constexpr int NB   = 256;   // batch
constexpr int NT   = 512;   // time steps
constexpr int NH   = 512;   // hidden
constexpr int NDIN = 64;    // input dim

constexpr int L0_KC = 18;   // K chunks of 32: 64(x) + 512(h0) = 576
constexpr int L1_KC = 32;   // 512(h0) + 512(h1) = 1024
constexpr int L0_IMG_HALVES = 4 * L0_KC * 64 * 8;  // 73728 B per htile
constexpr int L1_IMG_HALVES = 4 * L1_KC * 64 * 8;  // 131072 B per htile

// ws layout (bytes), all 256-aligned
constexpr size_t BAR_OFF   = 0;                        // 8 KB barrier counters
constexpr size_t BIAS0_OFF = 8192;                     // 2048 f32
constexpr size_t BIAS1_OFF = 16384;                    // 2048 f32
constexpr size_t H0R_OFF   = 24576;                    // [2][256][512] f16
constexpr size_t H1R_OFF   = H0R_OFF + 524288;         // [2][256][512] f16
constexpr size_t XT_OFF    = H1R_OFF + 524288;         // [512][256][64] f16
constexpr size_t W0I_OFF   = XT_OFF + 16777216;        // 32 htiles * 73728 B
constexpr size_t W1I_OFF   = W0I_OFF + 2359296;        // 32 htiles * 131072 B
constexpr size_t WS_NEED   = W1I_OFF + 4194304;        // ~24.4 MB

// ---------------------------------------------------------------------------
// Prep: swizzle weights (fp32 -> fp16) into MFMA B-fragment order.
// B-frag layout (16x16x32): lane L holds B[k = (L>>4)*8 + j][n = L&15], j=0..7
// Image element order: [htile][nf(=gate)][kc][lane][8 halves]
// ---------------------------------------------------------------------------
__global__ void prep_weights(const float* __restrict__ Wih0, const float* __restrict__ Whh0,
                             const float* __restrict__ Wih1, const float* __restrict__ Whh1,
                             char* __restrict__ ws) {
    int idx = blockIdx.x * 256 + threadIdx.x;
    const int L0_CH = 32 * 4 * L0_KC * 64;   // 147456
    const int L1_CH = 32 * 4 * L1_KC * 64;   // 262144
    if (idx < L0_CH) {
        int lam = idx & 63;
        int kc  = (idx >> 6) % L0_KC;
        int nf  = ((idx >> 6) / L0_KC) & 3;
        int ht  = idx / (64 * L0_KC * 4);
        int g   = nf * NH + ht * 16 + (lam & 15);   // gate row in [0,2048)
        int kb  = kc * 32 + (lam >> 4) * 8;
        f16x8 v;
#pragma unroll
        for (int j = 0; j < 8; ++j) {
            int k = kb + j;
            float val = (k < NDIN) ? Wih0[(size_t)g * NDIN + k]
                                   : Whh0[(size_t)g * NH + (k - NDIN)];
            v[j] = (f16)val;
        }
        f16* dst = (f16*)(ws + W0I_OFF) + (size_t)ht * L0_IMG_HALVES
                 + ((size_t)(nf * L0_KC + kc) * 64 + lam) * 8;
        *(f16x8*)dst = v;
    } else if (idx < L0_CH + L1_CH) {
        int i2  = idx - L0_CH;
        int lam = i2 & 63;
        int kc  = (i2 >> 6) % L1_KC;
        int nf  = ((i2 >> 6) / L1_KC) & 3;
        int ht  = i2 / (64 * L1_KC * 4);
        int g   = nf * NH + ht * 16 + (lam & 15);
        int kb  = kc * 32 + (lam >> 4) * 8;
        f16x8 v;
#pragma unroll
        for (int j = 0; j < 8; ++j) {
            int k = kb + j;
            float val = (k < NH) ? Wih1[(size_t)g * NH + k]
                                 : Whh1[(size_t)g * NH + (k - NH)];
            v[j] = (f16)val;
        }
        f16* dst = (f16*)(ws + W1I_OFF) + (size_t)ht * L1_IMG_HALVES
                 + ((size_t)(nf * L1_KC + kc) * 64 + lam) * 8;
        *(f16x8*)dst = v;
    }
}

// x [B][T][64] fp32 -> xt [T][B][64] fp16 (time-major)
__global__ void prep_x(const float* __restrict__ x, char* __restrict__ ws) {
    int idx = blockIdx.x * 256 + threadIdx.x;          // t*256*8 + b*8 + d8
    if (idx >= NT * NB * 8) return;
    int d8 = idx & 7;
    int b  = (idx >> 3) & 255;
    int t  = idx >> 11;
    const float* src = x + ((size_t)b * NT + t) * NDIN + d8 * 8;
    f16x8 v;
#pragma unroll
    for (int j = 0; j < 8; ++j) v[j] = (f16)src[j];
    f16* dst = (f16*)(ws + XT_OFF) + ((size_t)t * NB + b) * NDIN + d8 * 8;
    *(f16x8*)dst = v;
}

// bias sums + zero barrier area + zero h rings
__global__ void prep_state(const float* __restrict__ bih0, const float* __restrict__ bhh0,
                           const float* __restrict__ bih1, const float* __restrict__ bhh1,
                           char* __restrict__ ws) {
    int idx = blockIdx.x * 256 + threadIdx.x;
    if (idx < 2048) {
        ((float*)(ws + BIAS0_OFF))[idx] = bih0[idx] + bhh0[idx];
    } else if (idx < 4096) {
        int i = idx - 2048;
        ((float*)(ws + BIAS1_OFF))[i] = bih1[i] + bhh1[i];
    } else {
        int c = idx - 4096;
        uint4 z; z.x = z.y = z.z = z.w = 0u;
        if (c < 512) {                       // 8 KB barrier area
            ((uint4*)(ws + BAR_OFF))[c] = z;
        } else if (c < 512 + 65536) {        // both h rings (contiguous 1 MB)
            ((uint4*)(ws + H0R_OFF))[c - 512] = z;
        }
    }
}

// ---------------------------------------------------------------------------
// Persistent kernel
// ---------------------------------------------------------------------------
__device__ __forceinline__ float sigf(float x) { return 1.f / (1.f + __expf(-x)); }
__device__ __forceinline__ float tanhx(float x) { float e = __expf(2.f * x); return 1.f - 2.f / (e + 1.f); }

__device__ __forceinline__ void h_store(f16* p, float v) {
    // Agent-scope relaxed store: sc1 write-through to LLC. Required: up to 4
    // ht-blocks (possibly different XCDs) write disjoint 32B chunks of one
    // 128B line — dirty-L2 writeback would race; LLC byte-merge is safe.
    unsigned short u = __builtin_bit_cast(unsigned short, (f16)v);
    __hip_atomic_store((unsigned short*)p, u, __ATOMIC_RELAXED, __HIP_MEMORY_SCOPE_AGENT);
}

__global__ __launch_bounds__(256, 1) void lstm_persist(char* __restrict__ ws,
                                                       const float* __restrict__ fcW,
                                                       const float* __restrict__ fcb,
                                                       float* __restrict__ out) {
    extern __shared__ __align__(16) char smem[];
    f16*   sW   = (f16*)smem;                 // W image: up to 128 KB
    float* exch = (float*)(smem + 131072);    // 8 KB g/o exchange

    const int tid  = threadIdx.x;
    const int lam  = tid & 63;
    const int w    = tid >> 6;
    const int mh   = w & 1;          // M half (rows b0+mh*32 .. +31)
    const int nh   = w >> 1;         // N half: 0 -> gates i,f ; 1 -> gates g,o
    const int col  = lam & 15;
    const int quad = lam >> 4;

    // XCD-aware swizzle: blockIdx%8 selects (layer, b-tile) so all 32 ht-blocks
    // sharing one h slab land on one XCD (heuristic only — correctness never
    // depends on it; sc1 stores/LLC handle the general case).
    const int grp   = blockIdx.x & 7;
    const int layer = grp >> 2;              // 0..1
    const int b0    = (grp & 3) * 64;        // 4 B-tiles of 64
    const int ht    = blockIdx.x >> 3;       // 32 H-tiles of 16
    const int h0c   = ht * 16;
    const int KC    = layer ? L1_KC : L0_KC;

    f16* h0ring = (f16*)(ws + H0R_OFF);
    f16* h1ring = (f16*)(ws + H1R_OFF);
    const f16*   xt   = (const f16*)(ws + XT_OFF);
    const float* bias = (const float*)(ws + (layer ? BIAS1_OFF : BIAS0_OFF));
    const f16*   wimg = (const f16*)(ws + (layer ? W1I_OFF : W0I_OFF))
                      + (size_t)ht * (layer ? L1_IMG_HALVES : L0_IMG_HALVES);

    // Stage this block's W slice into LDS once (lives for all 512 steps).
    {
        const int n16 = KC * 4 * 64;         // uint4 chunks
        const uint4* src = (const uint4*)wimg;
        uint4* dst = (uint4*)sW;
        for (int i = tid; i < n16; i += 256) dst[i] = src[i];
    }
    __syncthreads();

    const float bi_i = bias[0 * NH + h0c + col];
    const float bi_f = bias[1 * NH + h0c + col];
    const float bi_g = bias[2 * NH + h0c + col];
    const float bi_o = bias[3 * NH + h0c + col];

    float cst[2][4];                          // c state (only meaningful in nh==0 waves)
#pragma unroll
    for (int a = 0; a < 2; ++a)
#pragma unroll
        for (int r = 0; r < 4; ++r) cst[a][r] = 0.f;

    unsigned* rootc = (unsigned*)(ws + BAR_OFF);
    unsigned* grpc  = (unsigned*)(ws + BAR_OFF + 256 + (size_t)(blockIdx.x >> 4) * 256);

    const f16x8* sBf = (const f16x8*)sW;
    const int nf0 = nh * 2, nf1 = nh * 2 + 1;
    const int rA0 = b0 + mh * 32 + col;       // A-row (m = lane&15) for m-frag 0; +16 for frag 1

    for (int s = 0; s <= NT; ++s) {
        const bool active = layer ? (s >= 1) : (s < NT);
        if (active) {
            f32x4 acc00 = {0.f,0.f,0.f,0.f}, acc01 = {0.f,0.f,0.f,0.f};
            f32x4 acc10 = {0.f,0.f,0.f,0.f}, acc11 = {0.f,0.f,0.f,0.f};

            if (layer == 0) {
                const f16* xa = xt + (size_t)s * NB * NDIN;
                const f16* hp = h0ring + (size_t)((s + 1) & 1) * (NB * NH);
#pragma unroll
                for (int kc = 0; kc < 2; ++kc) {          // x part (K 0..63)
                    int ko = kc * 32 + quad * 8;
                    f16x8 a0 = *(const f16x8*)(xa + (size_t)rA0 * NDIN + ko);
                    f16x8 a1 = *(const f16x8*)(xa + (size_t)(rA0 + 16) * NDIN + ko);
                    f16x8 w0 = sBf[(nf0 * L0_KC + kc) * 64 + lam];
                    f16x8 w1 = sBf[(nf1 * L0_KC + kc) * 64 + lam];
                    acc00 = __builtin_amdgcn_mfma_f32_16x16x32_f16(a0, w0, acc00, 0, 0, 0);
                    acc01 = __builtin_amdgcn_mfma_f32_16x16x32_f16(a0, w1, acc01, 0, 0, 0);
                    acc10 = __builtin_amdgcn_mfma_f32_16x16x32_f16(a1, w0, acc10, 0, 0, 0);
                    acc11 = __builtin_amdgcn_mfma_f32_16x16x32_f16(a1, w1, acc11, 0, 0, 0);
                }
#pragma unroll
                for (int kc = 2; kc < L0_KC; ++kc) {      // h0_{t-1} part
                    int ko = (kc - 2) * 32 + quad * 8;
                    f16x8 a0 = *(const f16x8*)(hp + (size_t)rA0 * NH + ko);
                    f16x8 a1 = *(const f16x8*)(hp + (size_t)(rA0 + 16) * NH + ko);
                    f16x8 w0 = sBf[(nf0 * L0_KC + kc) * 64 + lam];
                    f16x8 w1 = sBf[(nf1 * L0_KC + kc) * 64 + lam];
                    acc00 = __builtin_amdgcn_mfma_f32_16x16x32_f16(a0, w0, acc00, 0, 0, 0);
                    acc01 = __builtin_amdgcn_mfma_f32_16x16x32_f16(a0, w1, acc01, 0, 0, 0);
                    acc10 = __builtin_amdgcn_mfma_f32_16x16x32_f16(a1, w0, acc10, 0, 0, 0);
                    acc11 = __builtin_amdgcn_mfma_f32_16x16x32_f16(a1, w1, acc11, 0, 0, 0);
                }
            } else {
                const f16* hp0 = h0ring + (size_t)((s - 1) & 1) * (NB * NH);  // h0[t]
                const f16* hp1 = h1ring + (size_t)(s & 1) * (NB * NH);        // h1[t-1]
#pragma unroll
                for (int kc = 0; kc < 16; ++kc) {
                    int ko = kc * 32 + quad * 8;
                    f16x8 a0 = *(const f16x8*)(hp0 + (size_t)rA0 * NH + ko);
                    f16x8 a1 = *(const f16x8*)(hp0 + (size_t)(rA0 + 16) * NH + ko);
                    f16x8 w0 = sBf[(nf0 * L1_KC + kc) * 64 + lam];
                    f16x8 w1 = sBf[(nf1 * L1_KC + kc) * 64 + lam];
                    acc00 = __builtin_amdgcn_mfma_f32_16x16x32_f16(a0, w0, acc00, 0, 0, 0);
                    acc01 = __builtin_amdgcn_mfma_f32_16x16x32_f16(a0, w1, acc01, 0, 0, 0);
                    acc10 = __builtin_amdgcn_mfma_f32_16x16x32_f16(a1, w0, acc10, 0, 0, 0);
                    acc11 = __builtin_amdgcn_mfma_f32_16x16x32_f16(a1, w1, acc11, 0, 0, 0);
                }
#pragma unroll
                for (int kc = 16; kc < 32; ++kc) {
                    int ko = (kc - 16) * 32 + quad * 8;
                    f16x8 a0 = *(const f16x8*)(hp1 + (size_t)rA0 * NH + ko);
                    f16x8 a1 = *(const f16x8*)(hp1 + (size_t)(rA0 + 16) * NH + ko);
                    f16x8 w0 = sBf[(nf0 * L1_KC + kc) * 64 + lam];
                    f16x8 w1 = sBf[(nf1 * L1_KC + kc) * 64 + lam];
                    acc00 = __builtin_amdgcn_mfma_f32_16x16x32_f16(a0, w0, acc00, 0, 0, 0);
                    acc01 = __builtin_amdgcn_mfma_f32_16x16x32_f16(a0, w1, acc01, 0, 0, 0);
                    acc10 = __builtin_amdgcn_mfma_f32_16x16x32_f16(a1, w0, acc10, 0, 0, 0);
                    acc11 = __builtin_amdgcn_mfma_f32_16x16x32_f16(a1, w1, acc11, 0, 0, 0);
                }
            }

            // g/o waves hand their accs to i/f waves; cell update is register-local there.
            if (nh == 1) {
                f32x4* e4 = (f32x4*)exch;
                e4[((mh * 2 + 0) * 2 + 0) * 64 + lam] = acc00;   // mf0, gate g
                e4[((mh * 2 + 0) * 2 + 1) * 64 + lam] = acc01;   // mf0, gate o
                e4[((mh * 2 + 1) * 2 + 0) * 64 + lam] = acc10;   // mf1, gate g
                e4[((mh * 2 + 1) * 2 + 1) * 64 + lam] = acc11;   // mf1, gate o
            }
            __syncthreads();
            if (nh == 0) {
                const f32x4* e4 = (const f32x4*)exch;
                f32x4 gg0 = e4[((mh * 2 + 0) * 2 + 0) * 64 + lam];
                f32x4 oo0 = e4[((mh * 2 + 0) * 2 + 1) * 64 + lam];
                f32x4 gg1 = e4[((mh * 2 + 1) * 2 + 0) * 64 + lam];
                f32x4 oo1 = e4[((mh * 2 + 1) * 2 + 1) * 64 + lam];
                f16* hw = layer ? (h1ring + (size_t)((s - 1) & 1) * (NB * NH))
                                : (h0ring + (size_t)(s & 1) * (NB * NH));
#pragma unroll
                for (int mf = 0; mf < 2; ++mf) {
                    f32x4 ai = mf ? acc10 : acc00;
                    f32x4 af = mf ? acc11 : acc01;
                    f32x4 ag = mf ? gg1 : gg0;
                    f32x4 ao = mf ? oo1 : oo0;
#pragma unroll
                    for (int r = 0; r < 4; ++r) {
                        float iv = ai[r] + bi_i;
                        float fv = af[r] + bi_f;
                        float gv = ag[r] + bi_g;
                        float ov = ao[r] + bi_o;
                        float cc = sigf(fv) * cst[mf][r] + sigf(iv) * tanhx(gv);
                        cst[mf][r] = cc;
                        float hh = sigf(ov) * tanhx(cc);
                        // C/D layout: row = quad*4 + r, col = lane&15
                        h_store(&hw[(size_t)(b0 + mh * 32 + mf * 16 + quad * 4 + r) * NH + h0c + col], hh);
                    }
                }
            }
        }

        // ---- grid barrier: 1 release-add + relaxed spin + 1 acquire per BLOCK ----
        __syncthreads();   // all waves done; implicit vmcnt(0) drains sc1 h-stores
        if (tid == 0) {
            // RELEASE: belt-and-suspenders ordering of h-stores before arrival
            // (wbl2 is ~free: nothing in the loop dirties L2).
            unsigned prev = __hip_atomic_fetch_add(grpc, 1u, __ATOMIC_RELEASE, __HIP_MEMORY_SCOPE_AGENT);
            if ((prev & 15u) == 15u)
                __hip_atomic_fetch_add(rootc, 1u, __ATOMIC_RELEASE, __HIP_MEMORY_SCOPE_AGENT);
            const unsigned tgt = (unsigned)(s + 1) * 16u;
            // RELAXED spin: sc1 load straight from LLC, NO per-iteration buffer_inv
            while (__hip_atomic_load(rootc, __ATOMIC_RELAXED, __HIP_MEMORY_SCOPE_AGENT) < tgt)
                __builtin_amdgcn_s_sleep(2);
            // exactly one acquire (buffer_inv) per block per step so the plain
            // L2-cached h-fragment loads below see this step's LLC data
            (void)__hip_atomic_load(rootc, __ATOMIC_ACQUIRE, __HIP_MEMORY_SCOPE_AGENT);
        }
        __syncthreads();
    }

    // Final FC: out[b] = fc_b + sum_j fc_W[j] * h2[T-1][b][j]; h1 ring slot (T-1)&1 = 1
    if (blockIdx.x == 0) {
        const f16* hrow = h1ring + (size_t)1 * (NB * NH) + (size_t)tid * NH;
        float acc = fcb[0];
#pragma unroll 4
        for (int j = 0; j < NH; ++j) acc += fcW[j] * (float)hrow[j];
        out[tid] = acc;
    }
}

// ---------------------------------------------------------------------------
extern "C" void kernel_launch(void* const* d_in, const int* in_sizes, int n_in,
                              void* d_out, int out_size, void* d_ws, size_t ws_size,
                              hipStream_t stream) {
    const float* x    = (const float*)d_in[0];
    const float* Wih0 = (const float*)d_in[1];
    const float* Whh0 = (const float*)d_in[2];
    const float* bih0 = (const float*)d_in[3];
    const float* bhh0 = (const float*)d_in[4];
    const float* Wih1 = (const float*)d_in[5];
    const float* Whh1 = (const float*)d_in[6];
    const float* bih1 = (const float*)d_in[7];
    const float* bhh1 = (const float*)d_in[8];
    const float* fcW  = (const float*)d_in[9];
    const float* fcb  = (const float*)d_in[10];
    char*  ws  = (char*)d_ws;
    float* out = (float*)d_out;

    if (ws_size < WS_NEED) {  // deterministic failure instead of corruption
        hipMemsetAsync(d_out, 0, (size_t)out_size * sizeof(float), stream);
        return;
    }

    hipFuncSetAttribute(reinterpret_cast<const void*>(lstm_persist),
                        hipFuncAttributeMaxDynamicSharedMemorySize, 139264);

    prep_weights<<<1600, 256, 0, stream>>>(Wih0, Whh0, Wih1, Whh1, ws);
    prep_x<<<4096, 256, 0, stream>>>(x, ws);
    prep_state<<<274, 256, 0, stream>>>(bih0, bhh0, bih1, bhh1, ws);
    // 256 blocks, 139264 B dynamic LDS -> exactly 1 block/CU on 256 CUs (co-resident)
    lstm_persist<<<256, 256, 139264, stream>>>(ws, fcW, fcb, out);
}

// Round 3
// 8272.997 us; speedup vs baseline: 3.8970x; 1.0813x over previous
//
#include <hip/hip_runtime.h>

// ---------------------------------------------------------------------------
// 2-layer LSTM (B=256,T=512,H=512,DIN=64) + FC, persistent-kernel wavefront.
// Layer pipelining: at wavefront step s, layer0 computes t=s, layer1 t=s-1.
// fp16 MFMA (16x16x32) with fp32 accum; c-state in registers (fp32).
// R3: barrier broadcast redesign. R2's single rootc line was polled by all
// 256 blocks (~700M req/s vs ~100M/s LLC line service -> queueing ~15us/step).
// Now: 16 group arrival counters -> root (RMW-only, unpolled) -> releaser
// stores epoch to 16 per-group go-flag lines; 16 pollers/line, s_sleep(8).
// ---------------------------------------------------------------------------

typedef _Float16 f16;
typedef _Float16 f16x8 __attribute__((ext_vector_type(8)));
typedef float    f32x4 __attribute__((ext_vector_type(4)));

constexpr int NB   = 256;   // batch
constexpr int NT   = 512;   // time steps
constexpr int NH   = 512;   // hidden
constexpr int NDIN = 64;    // input dim

constexpr int L0_KC = 18;   // K chunks of 32: 64(x) + 512(h0) = 576
constexpr int L1_KC = 32;   // 512(h0) + 512(h1) = 1024
constexpr int L0_IMG_HALVES = 4 * L0_KC * 64 * 8;  // 73728 B per htile
constexpr int L1_IMG_HALVES = 4 * L1_KC * 64 * 8;  // 131072 B per htile

// ws layout (bytes), all 256-aligned
constexpr size_t BAR_OFF   = 0;                        // 8 KB barrier area
//   rootc        @ BAR_OFF + 0
//   grpc[g]      @ BAR_OFF + 128*(1+g)    g in [0,16)
//   goflag[g]    @ BAR_OFF + 4096 + 128*g
constexpr size_t BIAS0_OFF = 8192;                     // 2048 f32
constexpr size_t BIAS1_OFF = 16384;                    // 2048 f32
constexpr size_t H0R_OFF   = 24576;                    // [2][256][512] f16
constexpr size_t H1R_OFF   = H0R_OFF + 524288;         // [2][256][512] f16
constexpr size_t XT_OFF    = H1R_OFF + 524288;         // [512][256][64] f16
constexpr size_t W0I_OFF   = XT_OFF + 16777216;        // 32 htiles * 73728 B
constexpr size_t W1I_OFF   = W0I_OFF + 2359296;        // 32 htiles * 131072 B
constexpr size_t WS_NEED   = W1I_OFF + 4194304;        // ~24.4 MB

// ---------------------------------------------------------------------------
// Prep: swizzle weights (fp32 -> fp16) into MFMA B-fragment order.
// B-frag layout (16x16x32): lane L holds B[k = (L>>4)*8 + j][n = L&15], j=0..7
// Image element order: [htile][nf(=gate)][kc][lane][8 halves]
// ---------------------------------------------------------------------------
__global__ void prep_weights(const float* __restrict__ Wih0, const float* __restrict__ Whh0,
                             const float* __restrict__ Wih1, const float* __restrict__ Whh1,
                             char* __restrict__ ws) {
    int idx = blockIdx.x * 256 + threadIdx.x;
    const int L0_CH = 32 * 4 * L0_KC * 64;   // 147456
    const int L1_CH = 32 * 4 * L1_KC * 64;   // 262144
    if (idx < L0_CH) {
        int lam = idx & 63;
        int kc  = (idx >> 6) % L0_KC;
        int nf  = ((idx >> 6) / L0_KC) & 3;
        int ht  = idx / (64 * L0_KC * 4);
        int g   = nf * NH + ht * 16 + (lam & 15);   // gate row in [0,2048)
        int kb  = kc * 32 + (lam >> 4) * 8;
        f16x8 v;
#pragma unroll
        for (int j = 0; j < 8; ++j) {
            int k = kb + j;
            float val = (k < NDIN) ? Wih0[(size_t)g * NDIN + k]
                                   : Whh0[(size_t)g * NH + (k - NDIN)];
            v[j] = (f16)val;
        }
        f16* dst = (f16*)(ws + W0I_OFF) + (size_t)ht * L0_IMG_HALVES
                 + ((size_t)(nf * L0_KC + kc) * 64 + lam) * 8;
        *(f16x8*)dst = v;
    } else if (idx < L0_CH + L1_CH) {
        int i2  = idx - L0_CH;
        int lam = i2 & 63;
        int kc  = (i2 >> 6) % L1_KC;
        int nf  = ((i2 >> 6) / L1_KC) & 3;
        int ht  = i2 / (64 * L1_KC * 4);
        int g   = nf * NH + ht * 16 + (lam & 15);
        int kb  = kc * 32 + (lam >> 4) * 8;
        f16x8 v;
#pragma unroll
        for (int j = 0; j < 8; ++j) {
            int k = kb + j;
            float val = (k < NH) ? Wih1[(size_t)g * NH + k]
                                 : Whh1[(size_t)g * NH + (k - NH)];
            v[j] = (f16)val;
        }
        f16* dst = (f16*)(ws + W1I_OFF) + (size_t)ht * L1_IMG_HALVES
                 + ((size_t)(nf * L1_KC + kc) * 64 + lam) * 8;
        *(f16x8*)dst = v;
    }
}

// x [B][T][64] fp32 -> xt [T][B][64] fp16 (time-major)
__global__ void prep_x(const float* __restrict__ x, char* __restrict__ ws) {
    int idx = blockIdx.x * 256 + threadIdx.x;          // t*256*8 + b*8 + d8
    if (idx >= NT * NB * 8) return;
    int d8 = idx & 7;
    int b  = (idx >> 3) & 255;
    int t  = idx >> 11;
    const float* src = x + ((size_t)b * NT + t) * NDIN + d8 * 8;
    f16x8 v;
#pragma unroll
    for (int j = 0; j < 8; ++j) v[j] = (f16)src[j];
    f16* dst = (f16*)(ws + XT_OFF) + ((size_t)t * NB + b) * NDIN + d8 * 8;
    *(f16x8*)dst = v;
}

// bias sums + zero barrier area + zero h rings
__global__ void prep_state(const float* __restrict__ bih0, const float* __restrict__ bhh0,
                           const float* __restrict__ bih1, const float* __restrict__ bhh1,
                             char* __restrict__ ws) {
    int idx = blockIdx.x * 256 + threadIdx.x;
    if (idx < 2048) {
        ((float*)(ws + BIAS0_OFF))[idx] = bih0[idx] + bhh0[idx];
    } else if (idx < 4096) {
        int i = idx - 2048;
        ((float*)(ws + BIAS1_OFF))[i] = bih1[i] + bhh1[i];
    } else {
        int c = idx - 4096;
        uint4 z; z.x = z.y = z.z = z.w = 0u;
        if (c < 512) {                       // 8 KB barrier area
            ((uint4*)(ws + BAR_OFF))[c] = z;
        } else if (c < 512 + 65536) {        // both h rings (contiguous 1 MB)
            ((uint4*)(ws + H0R_OFF))[c - 512] = z;
        }
    }
}

// ---------------------------------------------------------------------------
// Persistent kernel
// ---------------------------------------------------------------------------
__device__ __forceinline__ float sigf(float x) { return 1.f / (1.f + __expf(-x)); }
__device__ __forceinline__ float tanhx(float x) { float e = __expf(2.f * x); return 1.f - 2.f / (e + 1.f); }

__device__ __forceinline__ void h_store(f16* p, float v) {
    // Agent-scope relaxed store: sc1 write-through to LLC. Required: up to 4
    // ht-blocks (possibly different XCDs) write disjoint 32B chunks of one
    // 128B line — dirty-L2 writeback would race; LLC byte-merge is safe.
    unsigned short u = __builtin_bit_cast(unsigned short, (f16)v);
    __hip_atomic_store((unsigned short*)p, u, __ATOMIC_RELAXED, __HIP_MEMORY_SCOPE_AGENT);
}

__global__ __launch_bounds__(256, 1) void lstm_persist(char* __restrict__ ws,
                                                       const float* __restrict__ fcW,
                                                       const float* __restrict__ fcb,
                                                       float* __restrict__ out) {
    extern __shared__ __align__(16) char smem[];
    f16*   sW   = (f16*)smem;                 // W image: up to 128 KB
    float* exch = (float*)(smem + 131072);    // 8 KB g/o exchange

    const int tid  = threadIdx.x;
    const int lam  = tid & 63;
    const int w    = tid >> 6;
    const int mh   = w & 1;          // M half (rows b0+mh*32 .. +31)
    const int nh   = w >> 1;         // N half: 0 -> gates i,f ; 1 -> gates g,o
    const int col  = lam & 15;
    const int quad = lam >> 4;

    // XCD-aware swizzle: blockIdx%8 selects (layer, b-tile) so all 32 ht-blocks
    // sharing one h slab land on one XCD (heuristic only — correctness never
    // depends on it; sc1 stores/LLC handle the general case).
    const int grp   = blockIdx.x & 7;
    const int layer = grp >> 2;              // 0..1
    const int b0    = (grp & 3) * 64;        // 4 B-tiles of 64
    const int ht    = blockIdx.x >> 3;       // 32 H-tiles of 16
    const int h0c   = ht * 16;
    const int KC    = layer ? L1_KC : L0_KC;

    f16* h0ring = (f16*)(ws + H0R_OFF);
    f16* h1ring = (f16*)(ws + H1R_OFF);
    const f16*   xt   = (const f16*)(ws + XT_OFF);
    const float* bias = (const float*)(ws + (layer ? BIAS1_OFF : BIAS0_OFF));
    const f16*   wimg = (const f16*)(ws + (layer ? W1I_OFF : W0I_OFF))
                      + (size_t)ht * (layer ? L1_IMG_HALVES : L0_IMG_HALVES);

    // Stage this block's W slice into LDS once (lives for all 512 steps).
    {
        const int n16 = KC * 4 * 64;         // uint4 chunks
        const uint4* src = (const uint4*)wimg;
        uint4* dst = (uint4*)sW;
        for (int i = tid; i < n16; i += 256) dst[i] = src[i];
    }
    __syncthreads();

    const float bi_i = bias[0 * NH + h0c + col];
    const float bi_f = bias[1 * NH + h0c + col];
    const float bi_g = bias[2 * NH + h0c + col];
    const float bi_o = bias[3 * NH + h0c + col];

    float cst[2][4];                          // c state (only meaningful in nh==0 waves)
#pragma unroll
    for (int a = 0; a < 2; ++a)
#pragma unroll
        for (int r = 0; r < 4; ++r) cst[a][r] = 0.f;

    const int gid = blockIdx.x >> 4;                    // arrival group [0,16)
    unsigned* rootc  = (unsigned*)(ws + BAR_OFF);
    unsigned* grpc   = (unsigned*)(ws + BAR_OFF + 128 + (size_t)gid * 128);
    unsigned* goflag = (unsigned*)(ws + BAR_OFF + 4096 + (size_t)gid * 128);
    unsigned* goall  = (unsigned*)(ws + BAR_OFF + 4096);

    const f16x8* sBf = (const f16x8*)sW;
    const int nf0 = nh * 2, nf1 = nh * 2 + 1;
    const int rA0 = b0 + mh * 32 + col;       // A-row (m = lane&15) for m-frag 0; +16 for frag 1

    for (int s = 0; s <= NT; ++s) {
        const bool active = layer ? (s >= 1) : (s < NT);
        if (active) {
            f32x4 acc00 = {0.f,0.f,0.f,0.f}, acc01 = {0.f,0.f,0.f,0.f};
            f32x4 acc10 = {0.f,0.f,0.f,0.f}, acc11 = {0.f,0.f,0.f,0.f};

            if (layer == 0) {
                const f16* xa = xt + (size_t)s * NB * NDIN;
                const f16* hp = h0ring + (size_t)((s + 1) & 1) * (NB * NH);
#pragma unroll
                for (int kc = 0; kc < 2; ++kc) {          // x part (K 0..63)
                    int ko = kc * 32 + quad * 8;
                    f16x8 a0 = *(const f16x8*)(xa + (size_t)rA0 * NDIN + ko);
                    f16x8 a1 = *(const f16x8*)(xa + (size_t)(rA0 + 16) * NDIN + ko);
                    f16x8 w0 = sBf[(nf0 * L0_KC + kc) * 64 + lam];
                    f16x8 w1 = sBf[(nf1 * L0_KC + kc) * 64 + lam];
                    acc00 = __builtin_amdgcn_mfma_f32_16x16x32_f16(a0, w0, acc00, 0, 0, 0);
                    acc01 = __builtin_amdgcn_mfma_f32_16x16x32_f16(a0, w1, acc01, 0, 0, 0);
                    acc10 = __builtin_amdgcn_mfma_f32_16x16x32_f16(a1, w0, acc10, 0, 0, 0);
                    acc11 = __builtin_amdgcn_mfma_f32_16x16x32_f16(a1, w1, acc11, 0, 0, 0);
                }
#pragma unroll
                for (int kc = 2; kc < L0_KC; ++kc) {      // h0_{t-1} part
                    int ko = (kc - 2) * 32 + quad * 8;
                    f16x8 a0 = *(const f16x8*)(hp + (size_t)rA0 * NH + ko);
                    f16x8 a1 = *(const f16x8*)(hp + (size_t)(rA0 + 16) * NH + ko);
                    f16x8 w0 = sBf[(nf0 * L0_KC + kc) * 64 + lam];
                    f16x8 w1 = sBf[(nf1 * L0_KC + kc) * 64 + lam];
                    acc00 = __builtin_amdgcn_mfma_f32_16x16x32_f16(a0, w0, acc00, 0, 0, 0);
                    acc01 = __builtin_amdgcn_mfma_f32_16x16x32_f16(a0, w1, acc01, 0, 0, 0);
                    acc10 = __builtin_amdgcn_mfma_f32_16x16x32_f16(a1, w0, acc10, 0, 0, 0);
                    acc11 = __builtin_amdgcn_mfma_f32_16x16x32_f16(a1, w1, acc11, 0, 0, 0);
                }
            } else {
                const f16* hp0 = h0ring + (size_t)((s - 1) & 1) * (NB * NH);  // h0[t]
                const f16* hp1 = h1ring + (size_t)(s & 1) * (NB * NH);        // h1[t-1]
#pragma unroll
                for (int kc = 0; kc < 16; ++kc) {
                    int ko = kc * 32 + quad * 8;
                    f16x8 a0 = *(const f16x8*)(hp0 + (size_t)rA0 * NH + ko);
                    f16x8 a1 = *(const f16x8*)(hp0 + (size_t)(rA0 + 16) * NH + ko);
                    f16x8 w0 = sBf[(nf0 * L1_KC + kc) * 64 + lam];
                    f16x8 w1 = sBf[(nf1 * L1_KC + kc) * 64 + lam];
                    acc00 = __builtin_amdgcn_mfma_f32_16x16x32_f16(a0, w0, acc00, 0, 0, 0);
                    acc01 = __builtin_amdgcn_mfma_f32_16x16x32_f16(a0, w1, acc01, 0, 0, 0);
                    acc10 = __builtin_amdgcn_mfma_f32_16x16x32_f16(a1, w0, acc10, 0, 0, 0);
                    acc11 = __builtin_amdgcn_mfma_f32_16x16x32_f16(a1, w1, acc11, 0, 0, 0);
                }
#pragma unroll
                for (int kc = 16; kc < 32; ++kc) {
                    int ko = (kc - 16) * 32 + quad * 8;
                    f16x8 a0 = *(const f16x8*)(hp1 + (size_t)rA0 * NH + ko);
                    f16x8 a1 = *(const f16x8*)(hp1 + (size_t)(rA0 + 16) * NH + ko);
                    f16x8 w0 = sBf[(nf0 * L1_KC + kc) * 64 + lam];
                    f16x8 w1 = sBf[(nf1 * L1_KC + kc) * 64 + lam];
                    acc00 = __builtin_amdgcn_mfma_f32_16x16x32_f16(a0, w0, acc00, 0, 0, 0);
                    acc01 = __builtin_amdgcn_mfma_f32_16x16x32_f16(a0, w1, acc01, 0, 0, 0);
                    acc10 = __builtin_amdgcn_mfma_f32_16x16x32_f16(a1, w0, acc10, 0, 0, 0);
                    acc11 = __builtin_amdgcn_mfma_f32_16x16x32_f16(a1, w1, acc11, 0, 0, 0);
                }
            }

            // g/o waves hand their accs to i/f waves; cell update is register-local there.
            if (nh == 1) {
                f32x4* e4 = (f32x4*)exch;
                e4[((mh * 2 + 0) * 2 + 0) * 64 + lam] = acc00;   // mf0, gate g
                e4[((mh * 2 + 0) * 2 + 1) * 64 + lam] = acc01;   // mf0, gate o
                e4[((mh * 2 + 1) * 2 + 0) * 64 + lam] = acc10;   // mf1, gate g
                e4[((mh * 2 + 1) * 2 + 1) * 64 + lam] = acc11;   // mf1, gate o
            }
            __syncthreads();
            if (nh == 0) {
                const f32x4* e4 = (const f32x4*)exch;
                f32x4 gg0 = e4[((mh * 2 + 0) * 2 + 0) * 64 + lam];
                f32x4 oo0 = e4[((mh * 2 + 0) * 2 + 1) * 64 + lam];
                f32x4 gg1 = e4[((mh * 2 + 1) * 2 + 0) * 64 + lam];
                f32x4 oo1 = e4[((mh * 2 + 1) * 2 + 1) * 64 + lam];
                f16* hw = layer ? (h1ring + (size_t)((s - 1) & 1) * (NB * NH))
                                : (h0ring + (size_t)(s & 1) * (NB * NH));
#pragma unroll
                for (int mf = 0; mf < 2; ++mf) {
                    f32x4 ai = mf ? acc10 : acc00;
                    f32x4 af = mf ? acc11 : acc01;
                    f32x4 ag = mf ? gg1 : gg0;
                    f32x4 ao = mf ? oo1 : oo0;
#pragma unroll
                    for (int r = 0; r < 4; ++r) {
                        float iv = ai[r] + bi_i;
                        float fv = af[r] + bi_f;
                        float gv = ag[r] + bi_g;
                        float ov = ao[r] + bi_o;
                        float cc = sigf(fv) * cst[mf][r] + sigf(iv) * tanhx(gv);
                        cst[mf][r] = cc;
                        float hh = sigf(ov) * tanhx(cc);
                        // C/D layout: row = quad*4 + r, col = lane&15
                        h_store(&hw[(size_t)(b0 + mh * 32 + mf * 16 + quad * 4 + r) * NH + h0c + col], hh);
                    }
                }
            }
        }

        // ---- grid barrier: tree arrivals + distributed go-flag broadcast ----
        __syncthreads();   // all waves done; drains sc1 h-stores (vmcnt)
        if (tid == 0) {
            const unsigned ep = (unsigned)(s + 1);
            unsigned prev = __hip_atomic_fetch_add(grpc, 1u, __ATOMIC_RELEASE, __HIP_MEMORY_SCOPE_AGENT);
            if ((prev & 15u) == 15u) {
                // group leader: arrive at root (acq_rel RMW; root is never polled)
                unsigned rprev = __hip_atomic_fetch_add(rootc, 1u, __ATOMIC_ACQ_REL, __HIP_MEMORY_SCOPE_AGENT);
                if (rprev == ep * 16u - 1u) {
                    // releaser: broadcast epoch to 16 per-group flag lines.
                    // Stores are control-dependent on the root RMW result.
#pragma unroll
                    for (int g2 = 0; g2 < 16; ++g2)
                        __hip_atomic_store(goall + (size_t)g2 * 32, ep,
                                           __ATOMIC_RELAXED, __HIP_MEMORY_SCOPE_AGENT);
                }
            }
            // distributed spin: 16 pollers per flag line, relaxed (no inv)
            while (__hip_atomic_load(goflag, __ATOMIC_RELAXED, __HIP_MEMORY_SCOPE_AGENT) < ep)
                __builtin_amdgcn_s_sleep(8);
            // exactly one acquire (inv) per block per step so plain L2-cached
            // h reads below see this step's LLC data
            (void)__hip_atomic_load(goflag, __ATOMIC_ACQUIRE, __HIP_MEMORY_SCOPE_AGENT);
        }
        __syncthreads();
    }

    // Final FC: out[b] = fc_b + sum_j fc_W[j] * h2[T-1][b][j]; h1 ring slot (T-1)&1 = 1
    if (blockIdx.x == 0) {
        const f16* hrow = h1ring + (size_t)1 * (NB * NH) + (size_t)tid * NH;
        float acc = fcb[0];
#pragma unroll 4
        for (int j = 0; j < NH; ++j) acc += fcW[j] * (float)hrow[j];
        out[tid] = acc;
    }
}

// ---------------------------------------------------------------------------
extern "C" void kernel_launch(void* const* d_in, const int* in_sizes, int n_in,
                              void* d_out, int out_size, void* d_ws, size_t ws_size,
                              hipStream_t stream) {
    const float* x    = (const float*)d_in[0];
    const float* Wih0 = (const float*)d_in[1];
    const float* Whh0 = (const float*)d_in[2];
    const float* bih0 = (const float*)d_in[3];
    const float* bhh0 = (const float*)d_in[4];
    const float* Wih1 = (const float*)d_in[5];
    const float* Whh1 = (const float*)d_in[6];
    const float* bih1 = (const float*)d_in[7];
    const float* bhh1 = (const float*)d_in[8];
    const float* fcW  = (const float*)d_in[9];
    const float* fcb  = (const float*)d_in[10];
    char*  ws  = (char*)d_ws;
    float* out = (float*)d_out;

    if (ws_size < WS_NEED) {  // deterministic failure instead of corruption
        hipMemsetAsync(d_out, 0, (size_t)out_size * sizeof(float), stream);
        return;
    }

    hipFuncSetAttribute(reinterpret_cast<const void*>(lstm_persist),
                        hipFuncAttributeMaxDynamicSharedMemorySize, 139264);

    prep_weights<<<1600, 256, 0, stream>>>(Wih0, Whh0, Wih1, Whh1, ws);
    prep_x<<<4096, 256, 0, stream>>>(x, ws);
    prep_state<<<274, 256, 0, stream>>>(bih0, bhh0, bih1, bhh1, ws);
    // 256 blocks, 139264 B dynamic LDS -> exactly 1 block/CU on 256 CUs (co-resident)
    lstm_persist<<<256, 256, 139264, stream>>>(ws, fcW, fcb, out);
}

// Round 4
// 7404.676 us; speedup vs baseline: 4.3540x; 1.1173x over previous
//
#include <hip/hip_runtime.h>

// ---------------------------------------------------------------------------
// 2-layer LSTM (B=256,T=512,H=512,DIN=64) + FC, persistent-kernel wavefront.
// R4: NO global barrier. 8 groups x 32 blocks (group = blockIdx&7, XCD-aligned
// heuristically). Producer/consumer sync via per-block u32 flags packed one
// line per group (no atomic RMWs at all): chain = store->flag / poll->inv->load
// (depth 4 LLC hops vs R3's ~7). h0 ring depth 4 (cross-layer WAR gated by
// partner-progress poll), h1 ring depth 2 (safe via own read-gate).
// fp16 MFMA (16x16x32), fp32 accum, c-state in registers.
// ---------------------------------------------------------------------------

typedef _Float16 f16;
typedef _Float16 f16x8 __attribute__((ext_vector_type(8)));
typedef float    f32x4 __attribute__((ext_vector_type(4)));

constexpr int NB   = 256;   // batch
constexpr int NT   = 512;   // time steps
constexpr int NH   = 512;   // hidden
constexpr int NDIN = 64;    // input dim

constexpr int L0_KC = 18;   // K chunks of 32: 64(x) + 512(h0) = 576
constexpr int L1_KC = 32;   // 512(h0) + 512(h1) = 1024
constexpr int L0_IMG_HALVES = 4 * L0_KC * 64 * 8;  // 73728 B per htile
constexpr int L1_IMG_HALVES = 4 * L1_KC * 64 * 8;  // 131072 B per htile

// ws layout (bytes), all 256-aligned
constexpr size_t BAR_OFF   = 0;                        // flag lines: 8 groups * 128 B
constexpr size_t BIAS0_OFF = 8192;                     // 2048 f32
constexpr size_t BIAS1_OFF = 16384;                    // 2048 f32
constexpr size_t H0R_OFF   = 24576;                    // [4][256][512] f16 = 1 MB
constexpr size_t H1R_OFF   = H0R_OFF + 1048576;        // [2][256][512] f16 = 512 KB
constexpr size_t XT_OFF    = H1R_OFF + 524288;         // [512][256][64] f16
constexpr size_t W0I_OFF   = XT_OFF + 16777216;        // 32 htiles * 73728 B
constexpr size_t W1I_OFF   = W0I_OFF + 2359296;        // 32 htiles * 131072 B
constexpr size_t WS_NEED   = W1I_OFF + 4194304;        // ~23.8 MB

// ---------------------------------------------------------------------------
// Prep: swizzle weights (fp32 -> fp16) into MFMA B-fragment order.
// B-frag layout (16x16x32): lane L holds B[k = (L>>4)*8 + j][n = L&15], j=0..7
// Image element order: [htile][nf(=gate)][kc][lane][8 halves]
// ---------------------------------------------------------------------------
__global__ void prep_weights(const float* __restrict__ Wih0, const float* __restrict__ Whh0,
                             const float* __restrict__ Wih1, const float* __restrict__ Whh1,
                             char* __restrict__ ws) {
    int idx = blockIdx.x * 256 + threadIdx.x;
    const int L0_CH = 32 * 4 * L0_KC * 64;   // 147456
    const int L1_CH = 32 * 4 * L1_KC * 64;   // 262144
    if (idx < L0_CH) {
        int lam = idx & 63;
        int kc  = (idx >> 6) % L0_KC;
        int nf  = ((idx >> 6) / L0_KC) & 3;
        int ht  = idx / (64 * L0_KC * 4);
        int g   = nf * NH + ht * 16 + (lam & 15);   // gate row in [0,2048)
        int kb  = kc * 32 + (lam >> 4) * 8;
        f16x8 v;
#pragma unroll
        for (int j = 0; j < 8; ++j) {
            int k = kb + j;
            float val = (k < NDIN) ? Wih0[(size_t)g * NDIN + k]
                                   : Whh0[(size_t)g * NH + (k - NDIN)];
            v[j] = (f16)val;
        }
        f16* dst = (f16*)(ws + W0I_OFF) + (size_t)ht * L0_IMG_HALVES
                 + ((size_t)(nf * L0_KC + kc) * 64 + lam) * 8;
        *(f16x8*)dst = v;
    } else if (idx < L0_CH + L1_CH) {
        int i2  = idx - L0_CH;
        int lam = i2 & 63;
        int kc  = (i2 >> 6) % L1_KC;
        int nf  = ((i2 >> 6) / L1_KC) & 3;
        int ht  = i2 / (64 * L1_KC * 4);
        int g   = nf * NH + ht * 16 + (lam & 15);
        int kb  = kc * 32 + (lam >> 4) * 8;
        f16x8 v;
#pragma unroll
        for (int j = 0; j < 8; ++j) {
            int k = kb + j;
            float val = (k < NH) ? Wih1[(size_t)g * NH + k]
                                 : Whh1[(size_t)g * NH + (k - NH)];
            v[j] = (f16)val;
        }
        f16* dst = (f16*)(ws + W1I_OFF) + (size_t)ht * L1_IMG_HALVES
                 + ((size_t)(nf * L1_KC + kc) * 64 + lam) * 8;
        *(f16x8*)dst = v;
    }
}

// x [B][T][64] fp32 -> xt [T][B][64] fp16 (time-major)
__global__ void prep_x(const float* __restrict__ x, char* __restrict__ ws) {
    int idx = blockIdx.x * 256 + threadIdx.x;          // t*256*8 + b*8 + d8
    if (idx >= NT * NB * 8) return;
    int d8 = idx & 7;
    int b  = (idx >> 3) & 255;
    int t  = idx >> 11;
    const float* src = x + ((size_t)b * NT + t) * NDIN + d8 * 8;
    f16x8 v;
#pragma unroll
    for (int j = 0; j < 8; ++j) v[j] = (f16)src[j];
    f16* dst = (f16*)(ws + XT_OFF) + ((size_t)t * NB + b) * NDIN + d8 * 8;
    *(f16x8*)dst = v;
}

// bias sums + zero flag area + zero h rings (1.5 MB)
__global__ void prep_state(const float* __restrict__ bih0, const float* __restrict__ bhh0,
                           const float* __restrict__ bih1, const float* __restrict__ bhh1,
                           char* __restrict__ ws) {
    int idx = blockIdx.x * 256 + threadIdx.x;
    if (idx < 2048) {
        ((float*)(ws + BIAS0_OFF))[idx] = bih0[idx] + bhh0[idx];
    } else if (idx < 4096) {
        int i = idx - 2048;
        ((float*)(ws + BIAS1_OFF))[i] = bih1[i] + bhh1[i];
    } else {
        int c = idx - 4096;
        uint4 z; z.x = z.y = z.z = z.w = 0u;
        if (c < 512) {                       // 8 KB flag/barrier area
            ((uint4*)(ws + BAR_OFF))[c] = z;
        } else if (c < 512 + 98304) {        // h0 (1 MB) + h1 (512 KB) contiguous
            ((uint4*)(ws + H0R_OFF))[c - 512] = z;
        }
    }
}

// ---------------------------------------------------------------------------
// Persistent kernel
// ---------------------------------------------------------------------------
__device__ __forceinline__ float sigf(float x) { return 1.f / (1.f + __expf(-x)); }
__device__ __forceinline__ float tanhx(float x) { float e = __expf(2.f * x); return 1.f - 2.f / (e + 1.f); }

__device__ __forceinline__ void h_store(f16* p, float v) {
    // Agent-scope relaxed store: sc1 write-through to LLC (cross-XCD safe;
    // 4 b-tile blocks write disjoint 32B chunks of one 128B line -> LLC merge).
    unsigned short u = __builtin_bit_cast(unsigned short, (f16)v);
    __hip_atomic_store((unsigned short*)p, u, __ATOMIC_RELAXED, __HIP_MEMORY_SCOPE_AGENT);
}

__device__ __forceinline__ void spin_ge(const unsigned* p, unsigned tgt) {
    while (__hip_atomic_load(p, __ATOMIC_RELAXED, __HIP_MEMORY_SCOPE_AGENT) < tgt)
        __builtin_amdgcn_s_sleep(4);
}

__global__ __launch_bounds__(256, 1) void lstm_persist(char* __restrict__ ws,
                                                       const float* __restrict__ fcW,
                                                       const float* __restrict__ fcb,
                                                       float* __restrict__ out) {
    extern __shared__ __align__(16) char smem[];
    f16*   sW   = (f16*)smem;                 // W image: up to 128 KB
    float* exch = (float*)(smem + 131072);    // 8 KB g/o exchange

    const int tid  = threadIdx.x;
    const int lam  = tid & 63;
    const int w    = tid >> 6;
    const int mh   = w & 1;          // M half (rows b0+mh*32 .. +31)
    const int nh   = w >> 1;         // N half: 0 -> gates i,f ; 1 -> gates g,o
    const int col  = lam & 15;
    const int quad = lam >> 4;

    const int gid   = blockIdx.x & 7;        // group (XCD-aligned heuristic)
    const int layer = gid >> 2;              // 0..1
    const int b0    = (gid & 3) * 64;        // 4 B-tiles of 64
    const int ht    = blockIdx.x >> 3;       // 32 H-tiles of 16
    const int h0c   = ht * 16;
    const int KC    = layer ? L1_KC : L0_KC;
    const int partner = layer ? (gid - 4) : (gid + 4);

    unsigned* flagsbase = (unsigned*)(ws + BAR_OFF);
    unsigned* ownflag   = flagsbase + (size_t)gid * 32;      // 128 B line per group
    unsigned* partflag  = flagsbase + (size_t)partner * 32;
    unsigned* myflag    = ownflag + ht;

    f16* h0ring = (f16*)(ws + H0R_OFF);
    f16* h1ring = (f16*)(ws + H1R_OFF);
    const f16*   xt   = (const f16*)(ws + XT_OFF);
    const float* bias = (const float*)(ws + (layer ? BIAS1_OFF : BIAS0_OFF));
    const f16*   wimg = (const f16*)(ws + (layer ? W1I_OFF : W0I_OFF))
                      + (size_t)ht * (layer ? L1_IMG_HALVES : L0_IMG_HALVES);

    // Stage this block's W slice into LDS once (lives for all 512 steps).
    {
        const int n16 = KC * 4 * 64;         // uint4 chunks
        const uint4* src = (const uint4*)wimg;
        uint4* dst = (uint4*)sW;
        for (int i = tid; i < n16; i += 256) dst[i] = src[i];
    }
    __syncthreads();

    const float bi_i = bias[0 * NH + h0c + col];
    const float bi_f = bias[1 * NH + h0c + col];
    const float bi_g = bias[2 * NH + h0c + col];
    const float bi_o = bias[3 * NH + h0c + col];

    float cst[2][4];                          // c state (nh==0 waves)
#pragma unroll
    for (int a = 0; a < 2; ++a)
#pragma unroll
        for (int r = 0; r < 4; ++r) cst[a][r] = 0.f;

    const f16x8* sBf = (const f16x8*)sW;
    const int nf0 = nh * 2, nf1 = nh * 2 + 1;
    const int rA0 = b0 + mh * 32 + col;       // A-row for m-frag 0; +16 for frag 1
    constexpr int PREF = 4;

    for (int s = 0; s < NT; ++s) {
        // ---- dependency polls (32 parallel lanes per flag line) ----
        if (layer == 0) {
            // read gate: own group finished step s-1 (h0[s-1] ready)
            if (tid < 32 && s > 0) spin_ge(ownflag + tid, (unsigned)s);
            // WAR gate: L1 partner finished step s-4 (we overwrite h0[s-4])
            if (tid >= 64 && tid < 96 && s >= 4) spin_ge(partflag + (tid - 64), (unsigned)(s - 3));
        } else {
            // read gate: L0 partner finished step s (h0[s] ready)
            if (tid < 32) spin_ge(partflag + tid, (unsigned)(s + 1));
            // read gate: own group finished step s-1 (h1[s-1] ready)
            if (tid >= 64 && tid < 96 && s > 0) spin_ge(ownflag + (tid - 64), (unsigned)s);
        }
        __syncthreads();
        if (tid == 0)   // one acquire (L2 inv) per block per step
            (void)__hip_atomic_load(myflag, __ATOMIC_ACQUIRE, __HIP_MEMORY_SCOPE_AGENT);
        __syncthreads();

        // ---- gate GEMM ----
        f32x4 acc00 = {0.f,0.f,0.f,0.f}, acc01 = {0.f,0.f,0.f,0.f};
        f32x4 acc10 = {0.f,0.f,0.f,0.f}, acc11 = {0.f,0.f,0.f,0.f};

        if (layer == 0) {
            const f16* xa = xt + (size_t)s * NB * NDIN;
            const f16* hp = h0ring + (size_t)((s - 1) & 3) * (NB * NH);   // s=0 -> slot 3 (zeros)
            auto ldA0 = [&](int kc) -> f16x8 {
                return (kc < 2) ? *(const f16x8*)(xa + (size_t)rA0 * NDIN + kc * 32 + quad * 8)
                                : *(const f16x8*)(hp + (size_t)rA0 * NH + (kc - 2) * 32 + quad * 8);
            };
            auto ldA1 = [&](int kc) -> f16x8 {
                return (kc < 2) ? *(const f16x8*)(xa + (size_t)(rA0 + 16) * NDIN + kc * 32 + quad * 8)
                                : *(const f16x8*)(hp + (size_t)(rA0 + 16) * NH + (kc - 2) * 32 + quad * 8);
            };
            f16x8 pa[PREF], pb[PREF];
#pragma unroll
            for (int p = 0; p < PREF; ++p) { pa[p] = ldA0(p); pb[p] = ldA1(p); }
#pragma unroll
            for (int kc = 0; kc < L0_KC; ++kc) {
                f16x8 a0 = pa[kc & (PREF - 1)], a1 = pb[kc & (PREF - 1)];
                if (kc + PREF < L0_KC) { pa[kc & (PREF - 1)] = ldA0(kc + PREF); pb[kc & (PREF - 1)] = ldA1(kc + PREF); }
                f16x8 w0 = sBf[(nf0 * L0_KC + kc) * 64 + lam];
                f16x8 w1 = sBf[(nf1 * L0_KC + kc) * 64 + lam];
                acc00 = __builtin_amdgcn_mfma_f32_16x16x32_f16(a0, w0, acc00, 0, 0, 0);
                acc01 = __builtin_amdgcn_mfma_f32_16x16x32_f16(a0, w1, acc01, 0, 0, 0);
                acc10 = __builtin_amdgcn_mfma_f32_16x16x32_f16(a1, w0, acc10, 0, 0, 0);
                acc11 = __builtin_amdgcn_mfma_f32_16x16x32_f16(a1, w1, acc11, 0, 0, 0);
            }
        } else {
            const f16* hp0 = h0ring + (size_t)(s & 3) * (NB * NH);        // h0[s]
            const f16* hp1 = h1ring + (size_t)((s - 1) & 1) * (NB * NH);  // h1[s-1]; s=0 -> slot 1 (zeros)
            auto ldA0 = [&](int kc) -> f16x8 {
                return (kc < 16) ? *(const f16x8*)(hp0 + (size_t)rA0 * NH + kc * 32 + quad * 8)
                                 : *(const f16x8*)(hp1 + (size_t)rA0 * NH + (kc - 16) * 32 + quad * 8);
            };
            auto ldA1 = [&](int kc) -> f16x8 {
                return (kc < 16) ? *(const f16x8*)(hp0 + (size_t)(rA0 + 16) * NH + kc * 32 + quad * 8)
                                 : *(const f16x8*)(hp1 + (size_t)(rA0 + 16) * NH + (kc - 16) * 32 + quad * 8);
            };
            f16x8 pa[PREF], pb[PREF];
#pragma unroll
            for (int p = 0; p < PREF; ++p) { pa[p] = ldA0(p); pb[p] = ldA1(p); }
#pragma unroll
            for (int kc = 0; kc < L1_KC; ++kc) {
                f16x8 a0 = pa[kc & (PREF - 1)], a1 = pb[kc & (PREF - 1)];
                if (kc + PREF < L1_KC) { pa[kc & (PREF - 1)] = ldA0(kc + PREF); pb[kc & (PREF - 1)] = ldA1(kc + PREF); }
                f16x8 w0 = sBf[(nf0 * L1_KC + kc) * 64 + lam];
                f16x8 w1 = sBf[(nf1 * L1_KC + kc) * 64 + lam];
                acc00 = __builtin_amdgcn_mfma_f32_16x16x32_f16(a0, w0, acc00, 0, 0, 0);
                acc01 = __builtin_amdgcn_mfma_f32_16x16x32_f16(a0, w1, acc01, 0, 0, 0);
                acc10 = __builtin_amdgcn_mfma_f32_16x16x32_f16(a1, w0, acc10, 0, 0, 0);
                acc11 = __builtin_amdgcn_mfma_f32_16x16x32_f16(a1, w1, acc11, 0, 0, 0);
            }
        }

        // g/o waves hand their accs to i/f waves; cell update is register-local there.
        if (nh == 1) {
            f32x4* e4 = (f32x4*)exch;
            e4[((mh * 2 + 0) * 2 + 0) * 64 + lam] = acc00;   // mf0, gate g
            e4[((mh * 2 + 0) * 2 + 1) * 64 + lam] = acc01;   // mf0, gate o
            e4[((mh * 2 + 1) * 2 + 0) * 64 + lam] = acc10;   // mf1, gate g
            e4[((mh * 2 + 1) * 2 + 1) * 64 + lam] = acc11;   // mf1, gate o
        }
        __syncthreads();
        if (nh == 0) {
            const f32x4* e4 = (const f32x4*)exch;
            f32x4 gg0 = e4[((mh * 2 + 0) * 2 + 0) * 64 + lam];
            f32x4 oo0 = e4[((mh * 2 + 0) * 2 + 1) * 64 + lam];
            f32x4 gg1 = e4[((mh * 2 + 1) * 2 + 0) * 64 + lam];
            f32x4 oo1 = e4[((mh * 2 + 1) * 2 + 1) * 64 + lam];
            f16* hw = layer ? (h1ring + (size_t)(s & 1) * (NB * NH))
                            : (h0ring + (size_t)(s & 3) * (NB * NH));
#pragma unroll
            for (int mf = 0; mf < 2; ++mf) {
                f32x4 ai = mf ? acc10 : acc00;
                f32x4 af = mf ? acc11 : acc01;
                f32x4 ag = mf ? gg1 : gg0;
                f32x4 ao = mf ? oo1 : oo0;
#pragma unroll
                for (int r = 0; r < 4; ++r) {
                    float iv = ai[r] + bi_i;
                    float fv = af[r] + bi_f;
                    float gv = ag[r] + bi_g;
                    float ov = ao[r] + bi_o;
                    float cc = sigf(fv) * cst[mf][r] + sigf(iv) * tanhx(gv);
                    cst[mf][r] = cc;
                    float hh = sigf(ov) * tanhx(cc);
                    // C/D layout: row = quad*4 + r, col = lane&15
                    h_store(&hw[(size_t)(b0 + mh * 32 + mf * 16 + quad * 4 + r) * NH + h0c + col], hh);
                }
            }
        }

        // ---- publish: all waves drained at this barrier, then one release store ----
        __syncthreads();
        if (tid == 0)
            __hip_atomic_store(myflag, (unsigned)(s + 1), __ATOMIC_RELEASE, __HIP_MEMORY_SCOPE_AGENT);
        __syncthreads();
    }

    // Final FC by block 0: wait for all 4 L1 groups at step NT, then reduce.
    if (blockIdx.x == 0) {
        if (tid < 128) spin_ge(flagsbase + 128 + tid, (unsigned)NT);  // groups 4..7
        __syncthreads();
        if (tid == 0)
            (void)__hip_atomic_load(flagsbase + 128, __ATOMIC_ACQUIRE, __HIP_MEMORY_SCOPE_AGENT);
        __syncthreads();
        const f16* hrow = h1ring + (size_t)1 * (NB * NH) + (size_t)tid * NH;  // slot (511)&1 = 1
        float acc = fcb[0];
#pragma unroll 4
        for (int j = 0; j < NH; ++j) acc += fcW[j] * (float)hrow[j];
        out[tid] = acc;
    }
}

// ---------------------------------------------------------------------------
extern "C" void kernel_launch(void* const* d_in, const int* in_sizes, int n_in,
                              void* d_out, int out_size, void* d_ws, size_t ws_size,
                              hipStream_t stream) {
    const float* x    = (const float*)d_in[0];
    const float* Wih0 = (const float*)d_in[1];
    const float* Whh0 = (const float*)d_in[2];
    const float* bih0 = (const float*)d_in[3];
    const float* bhh0 = (const float*)d_in[4];
    const float* Wih1 = (const float*)d_in[5];
    const float* Whh1 = (const float*)d_in[6];
    const float* bih1 = (const float*)d_in[7];
    const float* bhh1 = (const float*)d_in[8];
    const float* fcW  = (const float*)d_in[9];
    const float* fcb  = (const float*)d_in[10];
    char*  ws  = (char*)d_ws;
    float* out = (float*)d_out;

    if (ws_size < WS_NEED) {  // deterministic failure instead of corruption
        hipMemsetAsync(d_out, 0, (size_t)out_size * sizeof(float), stream);
        return;
    }

    hipFuncSetAttribute(reinterpret_cast<const void*>(lstm_persist),
                        hipFuncAttributeMaxDynamicSharedMemorySize, 139264);

    prep_weights<<<1600, 256, 0, stream>>>(Wih0, Whh0, Wih1, Whh1, ws);
    prep_x<<<4096, 256, 0, stream>>>(x, ws);
    prep_state<<<402, 256, 0, stream>>>(bih0, bhh0, bih1, bhh1, ws);
    // 256 blocks, 139264 B dynamic LDS -> exactly 1 block/CU on 256 CUs
    lstm_persist<<<256, 256, 139264, stream>>>(ws, fcW, fcb, out);
}